// Round 4
// baseline (505.189 us; speedup 1.0000x reference)
//
#include <hip/hip_runtime.h>
#include <hip/hip_bf16.h>

// Correlation layer: out[b, i*41+j, y, x] = (1/576) * sum_c in1[b,c,y,x]*in2[b,c,y-dy,x-dx]
// dx = 2i-20, dy = 2j-20 (i = m/41, j = m%41), zero padding outside.
// b=4, c=64, h=96, w=160, D=41. Output 413 MB fp32.
//
// R4 (from R1 structure; R3 swizzle was neutral -> reads are L3-resident, not the issue):
// Diagnosis: corr (~222us) is latency-bound at 3 blocks/CU with serial phase chains.
//  - gd staging in bf16: LDS 49.4KB -> 36.3KB -> 4 blocks/CU (+33% occupancy),
//    __launch_bounds__(256,4) to keep VGPR<=128. Extra rounding ~2.7e-5 after /576.
//  - Invalid rows (y2 out of range, 26% of blocks, 109MB of zeros) split into a
//    dedicated streaming zero_fill kernel (contiguous spans, NT dwordx4, ~17us);
//    invalid corr blocks early-exit.
//  - Store phase: dword read of 2 bf16 -> cvt -> NT dwordx2 (fewer instructions).

#define B_ 4
#define C_ 64
#define H_ 96
#define W_ 160
#define DD 41
#define HW_ (H_*W_)
#define RS 72            // s2 LDS row stride (64 ch + 8 pad) -> 144 B rows, 16B-aligned
#define GSH 162          // gd16 row stride (ushorts): even -> dword-aligned rows; 81 dwords/row

typedef __bf16 bf16x8 __attribute__((ext_vector_type(8)));
typedef float  f32x4  __attribute__((ext_vector_type(4)));
typedef float  f32x2  __attribute__((ext_vector_type(2)));
typedef unsigned int u32x4 __attribute__((ext_vector_type(4)));

// ---------------- Pass 0: zero-fill the invalid (zero-padded) output region ----------------
// For j<10: y in [76+2j, 96) is invalid (y2>=96). For j>10: y in [0, 2j-20) (y2<0).
// Per (b,i,j) this is ONE contiguous span of <=20 rows x 640B.
__global__ __launch_bounds__(256) void zero_fill(float* __restrict__ out) {
    int m = blockIdx.x;                  // (b*41 + i)*41 + j
    int j = m % DD;
    int t = m / DD;
    int i = t % DD;
    int b = t / DD;
    int y0, cnt;
    if (j < 10) { y0 = 76 + 2 * j; cnt = 20 - 2 * j; }
    else        { y0 = 0;          cnt = 2 * j - 20; }   // j==10 -> cnt 0
    if (cnt == 0) return;
    f32x4* p = (f32x4*)(out + ((size_t)((b * DD + i) * DD + j) * H_ + y0) * W_);
    int n4 = cnt * (W_ / 4);             // <= 800 dwordx4 chunks
    f32x4 z = {};
    for (int k = threadIdx.x; k < n4; k += 256)
        __builtin_nontemporal_store(z, p + k);
}

// ---------------- Pass 1: NCHW fp32 -> NHWC bf16 ----------------
__global__ void to_nhwc(const float* __restrict__ s1, const float* __restrict__ s2,
                        ushort* __restrict__ d1, ushort* __restrict__ d2) {
    int p = blockIdx.x * 256 + threadIdx.x;            // pixel id in [0, B*H*W)
    const float* src = blockIdx.y ? s2 : s1;
    ushort* dst = blockIdx.y ? d2 : d1;
    int b = p / HW_;
    int rem = p - b * HW_;
    const float* sp = src + (size_t)b * (C_ * HW_) + rem;
    unsigned words[32];
#pragma unroll
    for (int k = 0; k < 32; ++k) {
        union { float f; unsigned u; } lo, hi;
        lo.f = sp[(size_t)(2 * k) * HW_];              // coalesced across lanes
        hi.f = sp[(size_t)(2 * k + 1) * HW_];
        unsigned rl = (lo.u + 0x7FFFu + ((lo.u >> 16) & 1u)) >> 16;         // RNE
        unsigned rh = (hi.u + 0x7FFFu + ((hi.u >> 16) & 1u)) & 0xFFFF0000u; // RNE
        words[k] = rl | rh;
    }
    u32x4* dp = (u32x4*)(dst + (size_t)p * C_);
#pragma unroll
    for (int k = 0; k < 8; ++k) {
        u32x4 v = { words[4 * k], words[4 * k + 1], words[4 * k + 2], words[4 * k + 3] };
        dp[k] = v;
    }
}

// ---------------- Pass 2: correlation (valid rows only) ----------------
__global__ __launch_bounds__(256, 4) void corr_kernel(const ushort* __restrict__ in1w,
                                                      const ushort* __restrict__ in2w,
                                                      float* __restrict__ out) {
    __shared__ ushort s2[2 * 80 * RS];    // in2 row, parity-split: [par][u>>1][72] = 23040 B
    __shared__ ushort gd16[DD * GSH];     // banded Gram in bf16, 13284 B (total 36324 -> 4 blk/CU)

    const int y   = blockIdx.x;           // y fastest: concurrent blocks write adjacent rows
    const int j   = blockIdx.y;           // dy index
    const int b   = blockIdx.z;
    const int y2 = y + 20 - 2 * j;
    if (y2 < 0 || y2 >= H_) return;       // zeros handled by zero_fill (uniform exit)

    const int tid = threadIdx.x;
    const int lane = tid & 63;
    const int w    = tid >> 6;            // wave id 0..3

    // ---- stage in2 row y2 (160 px * 64 ch bf16 = 20 KB) into parity-split LDS
    const uint4* src = (const uint4*)(in2w + (size_t)((b * H_ + y2) * W_) * C_);
#pragma unroll
    for (int it = 0; it < 5; ++it) {
        int cidx = it * 256 + tid;            // 1280 chunks of 16 B
        int u  = cidx >> 3;
        int co = (cidx & 7) * 8;
        uint4 v = src[cidx];                  // fully coalesced
        *(uint4*)&s2[((u & 1) * 80 + (u >> 1)) * RS + co] = v;
    }
    __syncthreads();

    // ---- MFMA Gram tiles: 40 (Mtile,Ntile) products, 10 per wave
    const int quad = lane >> 4;
    const int l15  = lane & 15;
    const ushort* a_base = in1w + (size_t)((b * H_ + y) * W_) * C_;
    for (int t = 0; t < 10; ++t) {
        int p  = w * 10 + t;
        int mi = p >> 2;                      // M-tile 0..9 (0-4 even x, 5-9 odd x)
        int nt = p & 3;                       // N-tile (u) 0..3
        int par = (mi >= 5) ? 1 : 0;
        int x0  = (mi - 5 * par) * 32;        // 0,32,64,96,128
        // A fragment: A[m=lane&15][k=quad*8+jj], x = x0+par+2*m
        int xa = x0 + par + 2 * l15;
        const bf16x8* aptr = (const bf16x8*)(const void*)(a_base + xa * C_ + quad * 8);
        bf16x8 a0 = aptr[0];                  // k 0..31
        bf16x8 a1 = aptr[4];                  // k 32..63
        // B fragment: B[k=quad*8+jj][n=lane&15], u = u0 + 2*n (same parity as x)
        int u0 = x0 + par - 60 + 32 * nt;
        int u  = u0 + 2 * l15;
        bf16x8 b0 = {}, b1 = {};
        if (u >= 0 && u < W_) {
            const bf16x8* bptr =
                (const bf16x8*)(const void*)&s2[((u & 1) * 80 + (u >> 1)) * RS + quad * 8];
            b0 = bptr[0];
            b1 = bptr[4];
        }
        f32x4 acc = {};
        acc = __builtin_amdgcn_mfma_f32_16x16x32_bf16(a0, b0, acc, 0, 0, 0);
        acc = __builtin_amdgcn_mfma_f32_16x16x32_bf16(a1, b1, acc, 0, 0, 0);
        // ---- scatter band (as bf16): C/D layout col(n)=lane&15, row(m)=quad*4+reg
        // dx = x-u = 2(mx-nu) + 60 - 32*nt ; i = (dx+20)/2 = mx - nu - 16*nt + 40
#pragma unroll
        for (int r = 0; r < 4; ++r) {
            int mx = quad * 4 + r;
            int i  = mx - l15 - 16 * nt + 40;
            if (i >= 0 && i <= 40) {
                int x = x0 + par + 2 * mx;
                union { float f; unsigned u; } cv; cv.f = acc[r];
                unsigned rr = (cv.u + 0x7FFFu + ((cv.u >> 16) & 1u)) >> 16;  // RNE
                gd16[i * GSH + x] = (ushort)rr;   // each (i,x) written exactly once
            }
        }
    }
    __syncthreads();

    // ---- output pass: out[b, i*41+j, y, 0..159]; dword = 2 bf16 -> NT dwordx2
    const float scale = 1.0f / 576.0f;
    for (int i = w; i < DD; i += 4) {
        float* op = out + ((size_t)(b * (DD * DD) + i * DD + j) * H_ + y) * W_;
        const ushort* g = &gd16[i * GSH];
        unsigned d0 = *(const unsigned*)&g[2 * lane];          // x = 2*lane, 2*lane+1
        union { unsigned u; float f; } c0, c1;
        c0.u = d0 << 16;
        c1.u = d0 & 0xFFFF0000u;
        f32x2 v0; v0[0] = c0.f * scale; v0[1] = c1.f * scale;
        __builtin_nontemporal_store(v0, (f32x2*)(op + 2 * lane));
        if (lane < 16) {
            unsigned d1 = *(const unsigned*)&g[2 * (64 + lane)]; // x = 128+2*lane, +1
            union { unsigned u; float f; } c2, c3;
            c2.u = d1 << 16;
            c3.u = d1 & 0xFFFF0000u;
            f32x2 v1; v1[0] = c2.f * scale; v1[1] = c3.f * scale;
            __builtin_nontemporal_store(v1, (f32x2*)(op + 128 + 2 * lane));
        }
    }
}

extern "C" void kernel_launch(void* const* d_in, const int* in_sizes, int n_in,
                              void* d_out, int out_size, void* d_ws, size_t ws_size,
                              hipStream_t stream) {
    const float* in1 = (const float*)d_in[0];
    const float* in2 = (const float*)d_in[1];
    float* out = (float*)d_out;
    ushort* w1 = (ushort*)d_ws;                      // 4*96*160*64 bf16 = 7.86 MB
    ushort* w2 = w1 + (size_t)B_ * H_ * W_ * C_;     // second tensor
    // Pass 0: stream zeros into the invalid (padded) output region (~109 MB)
    zero_fill<<<dim3(B_ * DD * DD), 256, 0, stream>>>(out);
    // Pass 1: transpose+cast both inputs (B*H*W = 61440 pixels, 240 blocks x 2)
    to_nhwc<<<dim3((B_ * HW_) / 256, 2), 256, 0, stream>>>(in1, in2, w1, w2);
    // Pass 2: one block per (y, j, b), valid rows only
    corr_kernel<<<dim3(H_, DD, B_), 256, 0, stream>>>(w1, w2, out);
}

// Round 5
// 501.294 us; speedup vs baseline: 1.0078x; 1.0078x over previous
//
#include <hip/hip_runtime.h>
#include <hip/hip_bf16.h>

// Correlation layer: out[b, i*41+j, y, x] = (1/576) * sum_c in1[b,c,y,x]*in2[b,c,y-dy,x-dx]
// dx = 2i-20, dy = 2j-20 (i = m/41, j = m%41), zero padding outside.
// b=4, c=64, h=96, w=160, D=41. Output 413 MB fp32.
//
// R5 = R1 (best, 494us) with ONE change: the output store path.
// Evidence: corr writes ~290-413MB at only ~1.4 TB/s effective, while the
// harness fill sustains 6.2 TB/s on the same buffer with plain dwordx4.
// R1's nontemporal *dword* stores are no-allocate at L2 -> no write combining
// -> sub-line granules RMW at HBM (~4x write amplification ~ 6.3/4 = 1.6 TB/s,
// matching observation). Fix: gd stride 161->164 (16B-aligned rows), read gd
// via ds_read_b128, store PLAIN dwordx4 (40 lanes x 16B = one 640B row per
// wave-instr — exactly the fill's store pattern). Store instrs 33 -> 11.
// (R2 j-loop: regressed. R3 XCD swizzle: neutral, reads L3-resident.
//  R4 occupancy 3->4 blocks/CU: neutral. All reverted.)

#define B_ 4
#define C_ 64
#define H_ 96
#define W_ 160
#define DD 41
#define HW_ (H_*W_)
#define RS 72            // s2 LDS row stride (64 ch + 8 pad) -> 144 B rows, 16B-aligned
#define GS 164           // gd row stride (floats): 164*4B rows -> 16B-aligned for b128;
                         // scatter stride mod 32 = 4 -> <=2-way aliasing in quad groups (free)

typedef __bf16 bf16x8 __attribute__((ext_vector_type(8)));
typedef float  f32x4  __attribute__((ext_vector_type(4)));
typedef unsigned int u32x4 __attribute__((ext_vector_type(4)));

// ---------------- Pass 1: NCHW fp32 -> NHWC bf16 ----------------
__global__ void to_nhwc(const float* __restrict__ s1, const float* __restrict__ s2,
                        ushort* __restrict__ d1, ushort* __restrict__ d2) {
    int p = blockIdx.x * 256 + threadIdx.x;            // pixel id in [0, B*H*W)
    const float* src = blockIdx.y ? s2 : s1;
    ushort* dst = blockIdx.y ? d2 : d1;
    int b = p / HW_;
    int rem = p - b * HW_;
    const float* sp = src + (size_t)b * (C_ * HW_) + rem;
    unsigned words[32];
#pragma unroll
    for (int k = 0; k < 32; ++k) {
        union { float f; unsigned u; } lo, hi;
        lo.f = sp[(size_t)(2 * k) * HW_];              // coalesced across lanes
        hi.f = sp[(size_t)(2 * k + 1) * HW_];
        unsigned rl = (lo.u + 0x7FFFu + ((lo.u >> 16) & 1u)) >> 16;         // RNE
        unsigned rh = (hi.u + 0x7FFFu + ((hi.u >> 16) & 1u)) & 0xFFFF0000u; // RNE
        words[k] = rl | rh;
    }
    u32x4* dp = (u32x4*)(dst + (size_t)p * C_);
#pragma unroll
    for (int k = 0; k < 8; ++k) {
        u32x4 v = { words[4 * k], words[4 * k + 1], words[4 * k + 2], words[4 * k + 3] };
        dp[k] = v;
    }
}

// ---------------- Pass 2: correlation ----------------
__global__ __launch_bounds__(256) void corr_kernel(const ushort* __restrict__ in1w,
                                                   const ushort* __restrict__ in2w,
                                                   float* __restrict__ out) {
    __shared__ ushort s2[2 * 80 * RS];    // in2 row, parity-split: [par][u>>1][72]
    __shared__ float  gd[DD * GS];        // Gd[i][x], banded Gram, stride 164 (16B-aligned rows)

    const int y   = blockIdx.x;           // y fastest: concurrent blocks write adjacent rows
    const int j   = blockIdx.y;           // dy index
    const int b   = blockIdx.z;
    const int tid = threadIdx.x;
    const int lane = tid & 63;
    const int w    = tid >> 6;            // wave id 0..3
    const int y2 = y + 20 - 2 * j;
    const bool valid_row = (y2 >= 0) && (y2 < H_);

    if (valid_row) {
        // ---- stage in2 row y2 (160 px * 64 ch bf16 = 20 KB) into parity-split LDS
        const uint4* src = (const uint4*)(in2w + (size_t)((b * H_ + y2) * W_) * C_);
#pragma unroll
        for (int it = 0; it < 5; ++it) {
            int cidx = it * 256 + tid;            // 1280 chunks of 16 B
            int u  = cidx >> 3;
            int co = (cidx & 7) * 8;
            uint4 v = src[cidx];                  // fully coalesced
            *(uint4*)&s2[((u & 1) * 80 + (u >> 1)) * RS + co] = v;
        }
        __syncthreads();

        // ---- MFMA Gram tiles: 40 (Mtile,Ntile) products, 10 per wave
        const int quad = lane >> 4;
        const int l15  = lane & 15;
        const ushort* a_base = in1w + (size_t)((b * H_ + y) * W_) * C_;
        for (int t = 0; t < 10; ++t) {
            int p  = w * 10 + t;
            int mi = p >> 2;                      // M-tile 0..9 (0-4 even x, 5-9 odd x)
            int nt = p & 3;                       // N-tile (u) 0..3
            int par = (mi >= 5) ? 1 : 0;
            int x0  = (mi - 5 * par) * 32;        // 0,32,64,96,128
            // A fragment: A[m=lane&15][k=quad*8+jj], x = x0+par+2*m
            int xa = x0 + par + 2 * l15;
            const bf16x8* aptr = (const bf16x8*)(const void*)(a_base + xa * C_ + quad * 8);
            bf16x8 a0 = aptr[0];                  // k 0..31
            bf16x8 a1 = aptr[4];                  // k 32..63
            // B fragment: B[k=quad*8+jj][n=lane&15], u = u0 + 2*n (same parity as x)
            int u0 = x0 + par - 60 + 32 * nt;
            int u  = u0 + 2 * l15;
            bf16x8 b0 = {}, b1 = {};
            if (u >= 0 && u < W_) {
                const bf16x8* bptr =
                    (const bf16x8*)(const void*)&s2[((u & 1) * 80 + (u >> 1)) * RS + quad * 8];
                b0 = bptr[0];
                b1 = bptr[4];
            }
            f32x4 acc = {};
            acc = __builtin_amdgcn_mfma_f32_16x16x32_bf16(a0, b0, acc, 0, 0, 0);
            acc = __builtin_amdgcn_mfma_f32_16x16x32_bf16(a1, b1, acc, 0, 0, 0);
            // ---- scatter band: C/D layout col(n)=lane&15, row(m)=quad*4+reg
            // dx = x-u = 2(mx-nu) + 60 - 32*nt ; i = (dx+20)/2 = mx - nu - 16*nt + 40
#pragma unroll
            for (int r = 0; r < 4; ++r) {
                int mx = quad * 4 + r;
                int i  = mx - l15 - 16 * nt + 40;
                if (i >= 0 && i <= 40) {
                    int x = x0 + par + 2 * mx;
                    gd[i * GS + x] = acc[r];      // each (i,x) written exactly once
                }
            }
        }
        __syncthreads();
    }

    // ---- output pass: out[b, i*41+j, y, 0..159]; one 640B row per wave-instr,
    // PLAIN dwordx4 stores (L2 write-combined -- the 6.2 TB/s fill's pattern)
    const float scale = 1.0f / 576.0f;
    if (lane < 40) {
        for (int i = w; i < DD; i += 4) {
            float* op = out + ((size_t)(b * (DD * DD) + i * DD + j) * H_ + y) * W_ + 4 * lane;
            if (valid_row) {
                f32x4 v = *(const f32x4*)&gd[i * GS + 4 * lane];  // ds_read_b128
                v[0] *= scale; v[1] *= scale; v[2] *= scale; v[3] *= scale;
                *(f32x4*)op = v;
            } else {
                f32x4 z = {};
                *(f32x4*)op = z;
            }
        }
    }
}

extern "C" void kernel_launch(void* const* d_in, const int* in_sizes, int n_in,
                              void* d_out, int out_size, void* d_ws, size_t ws_size,
                              hipStream_t stream) {
    const float* in1 = (const float*)d_in[0];
    const float* in2 = (const float*)d_in[1];
    float* out = (float*)d_out;
    ushort* w1 = (ushort*)d_ws;                      // 4*96*160*64 bf16 = 7.86 MB
    ushort* w2 = w1 + (size_t)B_ * H_ * W_ * C_;     // second tensor
    // Pass 1: transpose+cast both inputs (B*H*W = 61440 pixels, 240 blocks x 2)
    to_nhwc<<<dim3((B_ * HW_) / 256, 2), 256, 0, stream>>>(in1, in2, w1, w2);
    // Pass 2: one block per (y, j, b) -- y fastest for write locality
    corr_kernel<<<dim3(H_, DD, B_), 256, 0, stream>>>(w1, w2, out);
}

// Round 6
// 448.199 us; speedup vs baseline: 1.1272x; 1.1185x over previous
//
#include <hip/hip_runtime.h>
#include <hip/hip_bf16.h>

// Correlation layer: out[b, i*41+j, y, x] = (1/576) * sum_c in1[b,c,y,x]*in2[b,c,y-dy,x-dx]
// dx = 2i-20, dy = 2j-20 (i = m/41, j = m%41), zero padding outside.
// b=4, c=64, h=96, w=160, D=41. Output 413 MB fp32.
//
// R6 = R5 with ONE change: A-fragment loads hoisted out of the MFMA t-loop.
// Theory: the t-loop issued 2 fresh GLOBAL loads (L2/L3-hit, ~200-900cy) per
// iteration straight into MFMA -- a 10-deep serialized latency chain per wave
// with only 3 waves/SIMD of TLP to hide it. Each wave only needs 3 distinct
// M-tiles (A0[3]/A1[3], k compile-time via the w&1 branch -> registers, no
// scratch). 6 dwordx4 loads issued before staging so their latency hides under
// stage+barrier; t-loop body is now LDS+MFMA only. Global loads/lane 20 -> 6.
// Ledger: R1 grid-swap -37us; R2 j-loop +23 (reverted); R3 XCD swizzle 0;
// R4 occupancy 0 (confounded); R5 plain-x4 stores 0 (noise).

#define B_ 4
#define C_ 64
#define H_ 96
#define W_ 160
#define DD 41
#define HW_ (H_*W_)
#define RS 72            // s2 LDS row stride (64 ch + 8 pad) -> 144 B rows, 16B-aligned
#define GS 164           // gd row stride (floats): 16B-aligned rows for b128 reads

typedef __bf16 bf16x8 __attribute__((ext_vector_type(8)));
typedef float  f32x4  __attribute__((ext_vector_type(4)));
typedef unsigned int u32x4 __attribute__((ext_vector_type(4)));

// ---------------- Pass 1: NCHW fp32 -> NHWC bf16 ----------------
__global__ void to_nhwc(const float* __restrict__ s1, const float* __restrict__ s2,
                        ushort* __restrict__ d1, ushort* __restrict__ d2) {
    int p = blockIdx.x * 256 + threadIdx.x;            // pixel id in [0, B*H*W)
    const float* src = blockIdx.y ? s2 : s1;
    ushort* dst = blockIdx.y ? d2 : d1;
    int b = p / HW_;
    int rem = p - b * HW_;
    const float* sp = src + (size_t)b * (C_ * HW_) + rem;
    unsigned words[32];
#pragma unroll
    for (int k = 0; k < 32; ++k) {
        union { float f; unsigned u; } lo, hi;
        lo.f = sp[(size_t)(2 * k) * HW_];              // coalesced across lanes
        hi.f = sp[(size_t)(2 * k + 1) * HW_];
        unsigned rl = (lo.u + 0x7FFFu + ((lo.u >> 16) & 1u)) >> 16;         // RNE
        unsigned rh = (hi.u + 0x7FFFu + ((hi.u >> 16) & 1u)) & 0xFFFF0000u; // RNE
        words[k] = rl | rh;
    }
    u32x4* dp = (u32x4*)(dst + (size_t)p * C_);
#pragma unroll
    for (int k = 0; k < 8; ++k) {
        u32x4 v = { words[4 * k], words[4 * k + 1], words[4 * k + 2], words[4 * k + 3] };
        dp[k] = v;
    }
}

// ---------------- Pass 2: correlation ----------------
__global__ __launch_bounds__(256) void corr_kernel(const ushort* __restrict__ in1w,
                                                   const ushort* __restrict__ in2w,
                                                   float* __restrict__ out) {
    __shared__ ushort s2[2 * 80 * RS];    // in2 row, parity-split: [par][u>>1][72]
    __shared__ float  gd[DD * GS];        // Gd[i][x], banded Gram, stride 164

    const int y   = blockIdx.x;           // y fastest: concurrent blocks write adjacent rows
    const int j   = blockIdx.y;           // dy index
    const int b   = blockIdx.z;
    const int tid = threadIdx.x;
    const int lane = tid & 63;
    const int w    = tid >> 6;            // wave id 0..3
    const int quad = lane >> 4;
    const int l15  = lane & 15;
    const int y2 = y + 20 - 2 * j;
    const bool valid_row = (y2 >= 0) && (y2 < H_);

    if (valid_row) {
        // ---- A-fragment hoist: wave w's pairs p = w*10+t span mi in {mi0,mi0+1,mi0+2}.
        // Issued FIRST so the ~200-900cy L2/L3 latency hides under staging+barrier.
        const ushort* a_base = in1w + (size_t)((b * H_ + y) * W_) * C_;
        const int mi0 = (w * 10) >> 2;
        bf16x8 A0[3], A1[3];
#pragma unroll
        for (int k = 0; k < 3; ++k) {
            int mi  = mi0 + k;
            int par = (mi >= 5) ? 1 : 0;
            int x0  = (mi - 5 * par) * 32;
            int xa  = x0 + par + 2 * l15;     // A[m=l15][ch], x = x0+par+2*m
            const bf16x8* aptr = (const bf16x8*)(const void*)(a_base + xa * C_ + quad * 8);
            A0[k] = aptr[0];                  // ch quad*8 .. +7
            A1[k] = aptr[4];                  // ch quad*8+32 .. +7
        }

        // ---- stage in2 row y2 (160 px * 64 ch bf16 = 20 KB) into parity-split LDS
        const uint4* src = (const uint4*)(in2w + (size_t)((b * H_ + y2) * W_) * C_);
#pragma unroll
        for (int it = 0; it < 5; ++it) {
            int cidx = it * 256 + tid;            // 1280 chunks of 16 B
            int u  = cidx >> 3;
            int co = (cidx & 7) * 8;
            uint4 v = src[cidx];                  // fully coalesced
            *(uint4*)&s2[((u & 1) * 80 + (u >> 1)) * RS + co] = v;
        }
        __syncthreads();

        // ---- MFMA Gram tiles: 40 (Mtile,Ntile) products, 10 per wave.
        // k = (t + 2*(w&1))>>2 is compile-time after unroll -> A0/A1 stay in regs.
#define MFMA_BODY(OFF)                                                               \
        _Pragma("unroll")                                                            \
        for (int t = 0; t < 10; ++t) {                                               \
            const int k   = (t + 2 * (OFF)) >> 2;                                    \
            const int mi  = mi0 + k;                                                 \
            const int nt  = (2 * w + t) & 3;       /* p&3, p = w*10+t */             \
            const int par = (mi >= 5) ? 1 : 0;                                       \
            const int x0  = (mi - 5 * par) * 32;                                     \
            const int u   = x0 + par - 60 + 32 * nt + 2 * l15;                       \
            bf16x8 b0 = {}, b1 = {};                                                 \
            if (u >= 0 && u < W_) {                                                  \
                const bf16x8* bptr =                                                 \
                    (const bf16x8*)(const void*)&s2[((u & 1) * 80 + (u >> 1)) * RS + quad * 8]; \
                b0 = bptr[0];                                                        \
                b1 = bptr[4];                                                        \
            }                                                                        \
            f32x4 acc = {};                                                          \
            acc = __builtin_amdgcn_mfma_f32_16x16x32_bf16(A0[k], b0, acc, 0, 0, 0);  \
            acc = __builtin_amdgcn_mfma_f32_16x16x32_bf16(A1[k], b1, acc, 0, 0, 0);  \
            _Pragma("unroll")                                                        \
            for (int r = 0; r < 4; ++r) {                                            \
                int mx = quad * 4 + r;                                               \
                int i  = mx - l15 - 16 * nt + 40;                                    \
                if (i >= 0 && i <= 40) {                                             \
                    int x = x0 + par + 2 * mx;                                       \
                    gd[i * GS + x] = acc[r];   /* each (i,x) written exactly once */ \
                }                                                                    \
            }                                                                        \
        }

        if ((w & 1) == 0) { MFMA_BODY(0) } else { MFMA_BODY(1) }
#undef MFMA_BODY
        __syncthreads();
    }

    // ---- output pass: out[b, i*41+j, y, 0..159]; one 640B row per wave-instr,
    // plain dwordx4 stores (L2 write-combined -- the 6.2 TB/s fill's pattern)
    const float scale = 1.0f / 576.0f;
    if (lane < 40) {
        for (int i = w; i < DD; i += 4) {
            float* op = out + ((size_t)(b * (DD * DD) + i * DD + j) * H_ + y) * W_ + 4 * lane;
            if (valid_row) {
                f32x4 v = *(const f32x4*)&gd[i * GS + 4 * lane];  // ds_read_b128
                v[0] *= scale; v[1] *= scale; v[2] *= scale; v[3] *= scale;
                *(f32x4*)op = v;
            } else {
                f32x4 z = {};
                *(f32x4*)op = z;
            }
        }
    }
}

extern "C" void kernel_launch(void* const* d_in, const int* in_sizes, int n_in,
                              void* d_out, int out_size, void* d_ws, size_t ws_size,
                              hipStream_t stream) {
    const float* in1 = (const float*)d_in[0];
    const float* in2 = (const float*)d_in[1];
    float* out = (float*)d_out;
    ushort* w1 = (ushort*)d_ws;                      // 4*96*160*64 bf16 = 7.86 MB
    ushort* w2 = w1 + (size_t)B_ * H_ * W_ * C_;     // second tensor
    // Pass 1: transpose+cast both inputs (B*H*W = 61440 pixels, 240 blocks x 2)
    to_nhwc<<<dim3((B_ * HW_) / 256, 2), 256, 0, stream>>>(in1, in2, w1, w2);
    // Pass 2: one block per (y, j, b) -- y fastest for write locality
    corr_kernel<<<dim3(H_, DD, B_), 256, 0, stream>>>(w1, w2, out);
}